// Round 1
// baseline (695.390 us; speedup 1.0000x reference)
//
#include <hip/hip_runtime.h>
#include <cstdint>
#include <cstddef>

#define THREADS 256

static constexpr int kB   = 2;
static constexpr int kC   = 128;
static constexpr int kCK  = 64;
static constexpr int kH   = 256, kW = 512;
static constexpr int kH2  = 128, kW2 = 256;
static constexpr int kImgC = kH2 * kW2;   // 32768 coarse px / image
static constexpr int kImgF = kH * kW;     // 131072 fine px / image
static constexpr int kNPc  = kB * kImgC;  // 65536
static constexpr int kNPf  = kB * kImgF;  // 262144

// ---------- device helpers ----------

__device__ __forceinline__ void fma4(float* a, float4 w, float xv) {
  a[0] += w.x * xv; a[1] += w.y * xv; a[2] += w.z * xv; a[3] += w.w * xv;
}

// acc[16] += sum_c W[c][og*16..+15] * X[c][px]; X layout [128][64], Wt tile [128][64]
__device__ __forceinline__ void gemv16(const float* __restrict__ A,
                                       const float* __restrict__ Bs,
                                       int px, int og, float* acc) {
  #pragma unroll 4
  for (int c = 0; c < 128; ++c) {
    float xv = A[c * 64 + px];
    const float4* wp = (const float4*)(Bs + c * 64 + og * 16);
    float4 w0 = wp[0], w1 = wp[1], w2 = wp[2], w3 = wp[3];
    fma4(acc + 0, w0, xv); fma4(acc + 4, w1, xv);
    fma4(acc + 8, w2, xv); fma4(acc + 12, w3, xv);
  }
}

// copy 8192 contiguous floats (a [128][64] Wt tile) into LDS
__device__ __forceinline__ void stage_w64(float* Bs, const float* src, int tid) {
  #pragma unroll
  for (int i = 0; i < 8; ++i) {
    int e = i * THREADS + tid;  // float4 index 0..2047
    ((float4*)Bs)[e] = ((const float4*)src)[e];
  }
}

// copy columns [h*64, h*64+64) of a [128][128] Wt into LDS as [128][64]
__device__ __forceinline__ void stage_whalf(float* Bs, const float* Wt, int h, int tid) {
  #pragma unroll
  for (int i = 0; i < 8; ++i) {
    int e  = i * THREADS + tid;  // float4 index 0..2047
    int c  = e >> 4;
    int o4 = e & 15;
    ((float4*)Bs)[e] = ((const float4*)(Wt + c * 128 + h * 64))[o4];
  }
}

// ---------- kernel 0: transpose weights to [c][o] ----------

__global__ __launch_bounds__(THREADS) void transpose_w(
    const float* __restrict__ Wq, const float* __restrict__ Wk,
    const float* __restrict__ Wvp, const float* __restrict__ Wvi,
    const float* __restrict__ Wout,
    float* __restrict__ Wk_t, float* __restrict__ Wvp_t, float* __restrict__ Wq_t,
    float* __restrict__ Wvi_t, float* __restrict__ Wout_t) {
  int t = blockIdx.x * THREADS + threadIdx.x;  // 0..16383
  int c = t >> 7, o = t & 127;
  if (o < 64) {
    Wk_t[c * 64 + o] = Wk[o * 128 + c];
    Wq_t[c * 64 + o] = Wq[o * 128 + c];
  }
  Wvp_t[c * 128 + o]  = Wvp[o * 128 + c];
  Wvi_t[c * 128 + o]  = Wvi[o * 128 + c];
  Wout_t[c * 128 + o] = Wout[o * 128 + c];
}

// ---------- kernel 1: coarse k,v ----------

__global__ __launch_bounds__(THREADS) void coarse_kv(
    const float* __restrict__ h_prev,
    const float* __restrict__ Wk_t, const float* __restrict__ bk,
    const float* __restrict__ Wvp_t, const float* __restrict__ bvp,
    float* __restrict__ kbuf, float* __restrict__ vbuf) {
  __shared__ float A[kC * 64];
  __shared__ float Bs[kC * 64];
  const int tid = threadIdx.x;
  const int px = tid & 63;
  const int og = tid >> 6;
  const int p0 = blockIdx.x * 64;
  const int b = p0 >> 15;            // /32768
  const int pix = p0 & (kImgC - 1);

  {
    const float* src = h_prev + (size_t)b * kC * kImgC + pix;
    #pragma unroll
    for (int i = 0; i < 32; ++i) {
      int e = i * THREADS + tid;
      int c = e >> 6, j = e & 63;
      A[e] = src[(size_t)c * kImgC + j];
    }
  }
  stage_w64(Bs, Wk_t, tid);
  __syncthreads();

  {  // k: 64 outputs
    float acc[16];
    #pragma unroll
    for (int i = 0; i < 16; ++i) acc[i] = bk[og * 16 + i];
    gemv16(A, Bs, px, og, acc);
    float* dst = kbuf + (size_t)(p0 + px) * kCK + og * 16;
    ((float4*)dst)[0] = make_float4(acc[0], acc[1], acc[2], acc[3]);
    ((float4*)dst)[1] = make_float4(acc[4], acc[5], acc[6], acc[7]);
    ((float4*)dst)[2] = make_float4(acc[8], acc[9], acc[10], acc[11]);
    ((float4*)dst)[3] = make_float4(acc[12], acc[13], acc[14], acc[15]);
  }

  for (int h = 0; h < 2; ++h) {  // v: 128 outputs, two 64-wide tiles
    __syncthreads();
    stage_whalf(Bs, Wvp_t, h, tid);
    __syncthreads();
    float acc[16];
    #pragma unroll
    for (int i = 0; i < 16; ++i) acc[i] = bvp[h * 64 + og * 16 + i];
    gemv16(A, Bs, px, og, acc);
    float* dst = vbuf + (size_t)(p0 + px) * kC + h * 64 + og * 16;
    ((float4*)dst)[0] = make_float4(acc[0], acc[1], acc[2], acc[3]);
    ((float4*)dst)[1] = make_float4(acc[4], acc[5], acc[6], acc[7]);
    ((float4*)dst)[2] = make_float4(acc[8], acc[9], acc[10], acc[11]);
    ((float4*)dst)[3] = make_float4(acc[12], acc[13], acc[14], acc[15]);
  }
}

// ---------- kernel 2: fused fine pass (q, attention, v_init, out conv) ----------

__global__ __launch_bounds__(THREADS) void fine_fused(
    const float* __restrict__ h_init,
    const float* __restrict__ Wq_t, const float* __restrict__ bq,
    const float* __restrict__ Wvi_t, const float* __restrict__ bvi,
    const float* __restrict__ Wout_t, const float* __restrict__ bout,
    const float* __restrict__ kbuf, const float* __restrict__ vbuf,
    float* __restrict__ out) {
  __shared__ float A[kC * 64];   // h_init tile, later t tile
  __shared__ float Bs[kC * 64];  // weight tile, aliased by score partials

  const int tid = threadIdx.x;
  const int px = tid & 63;
  const int og = tid >> 6;

  const int s0 = blockIdx.x * 64;   // fine-pixel base; tile = one row segment
  const int b = s0 >> 17;           // /131072
  const int pix = s0 & (kImgF - 1);
  const int y = pix >> 9;           // /512
  const int x0 = pix & (kW - 1);

  {
    const float* src = h_init + (size_t)b * kC * kImgF + pix;
    #pragma unroll
    for (int i = 0; i < 32; ++i) {
      int e = i * THREADS + tid;
      int c = e >> 6, j = e & 63;
      A[e] = src[(size_t)c * kImgF + j];
    }
  }
  stage_w64(Bs, Wq_t, tid);
  __syncthreads();

  // q: thread holds channels og*16..+15 of its pixel's query
  float q[16];
  #pragma unroll
  for (int i = 0; i < 16; ++i) q[i] = bq[og * 16 + i];
  gemv16(A, Bs, px, og, q);

  // v_init: thread holds channels {og*16..+15} and {64+og*16..+15}
  float vi[32];
  for (int h = 0; h < 2; ++h) {
    __syncthreads();
    stage_whalf(Bs, Wvi_t, h, tid);
    __syncthreads();
    float* acc = vi + h * 16;
    #pragma unroll
    for (int i = 0; i < 16; ++i) acc[i] = bvi[h * 64 + og * 16 + i];
    gemv16(A, Bs, px, og, acc);
  }
  __syncthreads();  // Bs now free -> score partial buffer

  // attention scores: partial dot over this thread's 16 q-channels
  const int y2 = y >> 1;
  const int x2 = (x0 + px) >> 1;
  const float* kb = kbuf + (size_t)b * kImgC * kCK;
  #pragma unroll
  for (int j = 0; j < 9; ++j) {
    const int yy = y2 + j / 3 - 1;
    const int xx = x2 + j % 3 - 1;
    float s = 0.f;  // zero-padded tap => score contribution exactly 0
    if (yy >= 0 && yy < kH2 && xx >= 0 && xx < kW2) {
      const float4* kp = (const float4*)(kb + ((size_t)yy * kW2 + xx) * kCK + og * 16);
      float4 k0 = kp[0], k1 = kp[1], k2 = kp[2], k3 = kp[3];
      s = q[0] * k0.x + q[1] * k0.y + q[2] * k0.z + q[3] * k0.w
        + q[4] * k1.x + q[5] * k1.y + q[6] * k1.z + q[7] * k1.w
        + q[8] * k2.x + q[9] * k2.y + q[10] * k2.z + q[11] * k2.w
        + q[12] * k3.x + q[13] * k3.y + q[14] * k3.z + q[15] * k3.w;
    }
    Bs[j * 256 + og * 64 + px] = s;
  }
  __syncthreads();

  // full scores (sum over 4 og partials), softmax over 9 taps (OOB taps = 0)
  float a[9];
  float m = -1e30f;
  #pragma unroll
  for (int j = 0; j < 9; ++j) {
    float s = Bs[j * 256 + px] + Bs[j * 256 + 64 + px]
            + Bs[j * 256 + 128 + px] + Bs[j * 256 + 192 + px];
    a[j] = s;
    m = fmaxf(m, s);
  }
  float den = 0.f;
  #pragma unroll
  for (int j = 0; j < 9; ++j) { a[j] = __expf(a[j] - m); den += a[j]; }
  const float inv = 1.f / den;

  // x_att over this thread's 32 channels; t = v_init + x_att
  float xa[32];
  #pragma unroll
  for (int i = 0; i < 32; ++i) xa[i] = 0.f;
  const float* vb = vbuf + (size_t)b * kImgC * kC;
  #pragma unroll
  for (int j = 0; j < 9; ++j) {
    const int yy = y2 + j / 3 - 1;
    const int xx = x2 + j % 3 - 1;
    if (yy >= 0 && yy < kH2 && xx >= 0 && xx < kW2) {
      const float aj = a[j] * inv;
      const float* vrow = vb + ((size_t)yy * kW2 + xx) * kC;
      const float4* vp = (const float4*)(vrow + og * 16);
      const float4* vq = (const float4*)(vrow + 64 + og * 16);
      float4 v0 = vp[0], v1 = vp[1], v2 = vp[2], v3 = vp[3];
      float4 w0 = vq[0], w1 = vq[1], w2 = vq[2], w3 = vq[3];
      fma4(xa + 0, v0, aj);  fma4(xa + 4, v1, aj);
      fma4(xa + 8, v2, aj);  fma4(xa + 12, v3, aj);
      fma4(xa + 16, w0, aj); fma4(xa + 20, w1, aj);
      fma4(xa + 24, w2, aj); fma4(xa + 28, w3, aj);
    }
  }
  // write t into A (h_init tile is dead)
  #pragma unroll
  for (int i = 0; i < 16; ++i) {
    A[(og * 16 + i) * 64 + px]      = vi[i] + xa[i];
    A[(64 + og * 16 + i) * 64 + px] = vi[16 + i] + xa[16 + i];
  }

  // out = Wout @ t + bout, two 64-wide output tiles
  for (int h = 0; h < 2; ++h) {
    __syncthreads();  // h=0: also fences t-writes & score reads before Bs overwrite
    stage_whalf(Bs, Wout_t, h, tid);
    __syncthreads();
    float acc[16];
    #pragma unroll
    for (int i = 0; i < 16; ++i) acc[i] = bout[h * 64 + og * 16 + i];
    gemv16(A, Bs, px, og, acc);
    float* op = out + (size_t)b * kC * kImgF + (size_t)(h * 64 + og * 16) * kImgF
              + (size_t)y * kW + x0 + px;
    #pragma unroll
    for (int i = 0; i < 16; ++i) op[(size_t)i * kImgF] = acc[i];
  }
}

// ---------- launch ----------

extern "C" void kernel_launch(void* const* d_in, const int* in_sizes, int n_in,
                              void* d_out, int out_size, void* d_ws, size_t ws_size,
                              hipStream_t stream) {
  const float* h_prev = (const float*)d_in[0];
  const float* h_init = (const float*)d_in[1];
  const float* Wq   = (const float*)d_in[2];
  const float* bq   = (const float*)d_in[3];
  const float* Wk   = (const float*)d_in[4];
  const float* bk   = (const float*)d_in[5];
  const float* Wvp  = (const float*)d_in[6];
  const float* bvp  = (const float*)d_in[7];
  const float* Wvi  = (const float*)d_in[8];
  const float* bvi  = (const float*)d_in[9];
  const float* Wout = (const float*)d_in[10];
  const float* bout = (const float*)d_in[11];
  float* out = (float*)d_out;

  float* ws = (float*)d_ws;
  float* Wk_t   = ws;                          // 128*64
  float* Wvp_t  = Wk_t + 128 * 64;             // 128*128
  float* Wq_t   = Wvp_t + 128 * 128;           // 128*64
  float* Wvi_t  = Wq_t + 128 * 64;             // 128*128
  float* Wout_t = Wvi_t + 128 * 128;           // 128*128
  float* kbuf   = Wout_t + 128 * 128;          // 65536*64
  float* vbuf   = kbuf + (size_t)kNPc * kCK;   // 65536*128

  transpose_w<<<64, THREADS, 0, stream>>>(Wq, Wk, Wvp, Wvi, Wout,
                                          Wk_t, Wvp_t, Wq_t, Wvi_t, Wout_t);
  coarse_kv<<<kNPc / 64, THREADS, 0, stream>>>(h_prev, Wk_t, bk, Wvp_t, bvp, kbuf, vbuf);
  fine_fused<<<kNPf / 64, THREADS, 0, stream>>>(h_init, Wq_t, bq, Wvi_t, bvi,
                                                Wout_t, bout, kbuf, vbuf, out);
}

// Round 3
// 600.176 us; speedup vs baseline: 1.1586x; 1.1586x over previous
//
#include <hip/hip_runtime.h>
#include <cstdint>
#include <cstddef>

#define THREADS 256

typedef __attribute__((ext_vector_type(8))) short short8;   // 8 bf16 = 4 VGPR (MFMA A/B frag)
typedef __attribute__((ext_vector_type(4))) float f32x4;    // MFMA C/D frag

#define MFMA(a, b, c) __builtin_amdgcn_mfma_f32_16x16x32_bf16((a), (b), (c), 0, 0, 0)

static constexpr int kC    = 128;
static constexpr int kImgC = 128 * 256;   // 32768 coarse px / image
static constexpr int kImgF = 256 * 512;   // 131072 fine px / image

// fp32 -> bf16 RNE (integer math; inputs are never NaN here)
__device__ __forceinline__ unsigned short f2bf(float f) {
  unsigned u = __builtin_bit_cast(unsigned, f);
  u += 0x7fffu + ((u >> 16) & 1u);
  return (unsigned short)(u >> 16);
}
// pack two floats -> bf16x2 as uint (lo in low half)
__device__ __forceinline__ unsigned pack_bf16(float lo, float hi) {
  return (unsigned)f2bf(lo) | ((unsigned)f2bf(hi) << 16);
}
__device__ __forceinline__ float bf_up(unsigned short u) {
  return __builtin_bit_cast(float, (unsigned)u << 16);
}

// ---- stage 64px x 128ch fp32 tile -> LDS swizzled bf16 A-tile ----
// element (px,c) at byte: px*256 + (((c>>3) ^ (px&7))*16) + (c&7)*2
// global loads: 8 c-rows x 8 px per wave-inst (32B segments); LDS writes ~2-way.
__device__ __forceinline__ void stage_tile(char* lds, const float* __restrict__ src,
                                           size_t cstride, int tid) {
  const int l = tid & 63, w = tid >> 6;
  const int pxl = l & 7;
  const int cg  = l >> 3;
  #pragma unroll
  for (int i = 0; i < 16; ++i) {
    const int px = pxl + 8 * (i & 7);
    const int c  = 2 * (cg + 8 * (w + 4 * (i >> 3)));   // even, 0..126
    float f0 = src[(size_t)c * cstride + px];
    float f1 = src[(size_t)(c + 1) * cstride + px];
    const int chunk = (c >> 3) ^ (px & 7);
    *(unsigned*)(lds + px * 256 + chunk * 16 + (c & 7) * 2) = pack_bf16(f0, f1);
  }
}

// A-frag: lane l supplies A[m=px][k=c]: px = mt*16+(l&15), c = kt*32+(l>>4)*8+j
__device__ __forceinline__ short8 ldA(const char* lds, int mt, int kt, int l) {
  const int px = mt * 16 + (l & 15);
  const int chunk = (kt * 4 + (l >> 4)) ^ (px & 7);
  return *(const short8*)(lds + px * 256 + chunk * 16);
}

// ---------- kernel 0: cast all weights fp32 [o][c] -> bf16 [o][c] ----------
// wbuf layout (shorts): Wq@0(8192) Wk@8192(8192) Wvp@16384(16384) Wvi@32768(16384) Wout@49152(16384)
__global__ __launch_bounds__(THREADS) void cast_w(
    const float* __restrict__ Wq, const float* __restrict__ Wk,
    const float* __restrict__ Wvp, const float* __restrict__ Wvi,
    const float* __restrict__ Wout, unsigned short* __restrict__ dst) {
  int i = blockIdx.x * THREADS + threadIdx.x;   // 0..65535
  float v;
  if (i < 8192)       v = Wq[i];
  else if (i < 16384) v = Wk[i - 8192];
  else if (i < 32768) v = Wvp[i - 16384];
  else if (i < 49152) v = Wvi[i - 32768];
  else                v = Wout[i - 49152];
  dst[i] = f2bf(v);
}

// ---------- kernel 1: coarse k,v via MFMA ----------
__global__ __launch_bounds__(THREADS, 4) void coarse_kv(
    const float* __restrict__ h_prev, const unsigned short* __restrict__ wbuf,
    const float* __restrict__ bk, const float* __restrict__ bvp,
    float* __restrict__ kbuf, float* __restrict__ vbuf) {
  __shared__ char xs[16384];
  const int tid = threadIdx.x;
  const int l = tid & 63, w = tid >> 6;
  const int m = l & 15, g = l >> 4;
  const int chq = w * 16 + m;

  const int tile = blockIdx.x;              // 0..1023
  const int b    = tile >> 9;
  const int p0   = (tile & 511) * 64;       // within-image coarse px base
  const int p0g  = tile * 64;               // global coarse px base

  const short8* wkp = (const short8*)(wbuf + 8192);
  const short8* wvp = (const short8*)(wbuf + 16384);
  short8 fk[4], fv[2][4];
  #pragma unroll
  for (int kt = 0; kt < 4; ++kt) fk[kt] = wkp[chq * 16 + kt * 4 + g];
  #pragma unroll
  for (int nt = 0; nt < 2; ++nt)
    #pragma unroll
    for (int kt = 0; kt < 4; ++kt)
      fv[nt][kt] = wvp[(nt * 64 + chq) * 16 + kt * 4 + g];

  stage_tile(xs, h_prev + (size_t)b * kC * kImgC + p0, kImgC, tid);
  __syncthreads();

  {  // k: 64 out channels
    const float bl = bk[chq];
    #pragma unroll
    for (int mt = 0; mt < 4; ++mt) {
      f32x4 acc = {bl, bl, bl, bl};
      #pragma unroll
      for (int kt = 0; kt < 4; ++kt) acc = MFMA(ldA(xs, mt, kt, l), fk[kt], acc);
      #pragma unroll
      for (int r = 0; r < 4; ++r)
        kbuf[(size_t)(p0g + mt * 16 + g * 4 + r) * 64 + chq] = acc[r];
    }
  }
  #pragma unroll
  for (int nt = 0; nt < 2; ++nt) {  // v: 128 out channels
    const float bl = bvp[nt * 64 + chq];
    #pragma unroll
    for (int mt = 0; mt < 4; ++mt) {
      f32x4 acc = {bl, bl, bl, bl};
      #pragma unroll
      for (int kt = 0; kt < 4; ++kt) acc = MFMA(ldA(xs, mt, kt, l), fv[nt][kt], acc);
      #pragma unroll
      for (int r = 0; r < 4; ++r)
        vbuf[(size_t)(p0g + mt * 16 + g * 4 + r) * 128 + nt * 64 + chq] = acc[r];
    }
  }
}

// ---------- kernel 2: fused fine pass (q, attention, v_init, out conv) ----------
__global__ __launch_bounds__(THREADS, 3) void fine_fused(
    const float* __restrict__ h_init, const unsigned short* __restrict__ wbuf,
    const float* __restrict__ bq, const float* __restrict__ bvi,
    const float* __restrict__ bout,
    const float* __restrict__ kbuf, const float* __restrict__ vbuf,
    float* __restrict__ out) {
  __shared__ char xs[16384];                  // x-tile, later t-tile (swizzled bf16)
  __shared__ unsigned short qs[64 * 72];      // q  [px][72]  (stride 144 B)
  __shared__ unsigned short vis[128 * 66];    // vi [ch][66]  (stride 132 B)
  __shared__ float part[9 * 256];             // score partials

  const int tid = threadIdx.x;
  const int l = tid & 63, w = tid >> 6;
  const int m = l & 15, g = l >> 4;
  const int chq = w * 16 + m;
  const int px_t = l;                          // attention-phase pixel; og = w

  const short8* wqp = (const short8*)wbuf;
  const short8* wip = (const short8*)(wbuf + 32768);
  const short8* wop = (const short8*)(wbuf + 49152);
  const float bql = bq[chq];
  const float bil0 = bvi[chq], bil1 = bvi[64 + chq];
  const float bol0 = bout[chq], bol1 = bout[64 + chq];

  const int rix = blockIdx.x;                  // same (y,x0) for both images
  const int y  = rix >> 3;
  const int x0 = (rix & 7) * 64;
  const int y2 = y >> 1;
  const int x2 = (x0 + px_t) >> 1;

  for (int t2 = 0; t2 < 2; ++t2) {
    const int b = t2;
    const size_t fbase = (size_t)b * kC * kImgF;

    __syncthreads();   // protect all LDS reuse across loop iterations
    stage_tile(xs, h_init + fbase + (size_t)y * 512 + x0, kImgF, tid);
    __syncthreads();

    // ---- GEMM1: q = x * Wq^T  -> qs (bf16) ----
    #pragma unroll
    for (int mt = 0; mt < 4; ++mt) {
      short8 fq[4];
      #pragma unroll
      for (int kt = 0; kt < 4; ++kt) fq[kt] = wqp[chq * 16 + kt * 4 + g];
      f32x4 acc = {bql, bql, bql, bql};
      #pragma unroll
      for (int kt = 0; kt < 4; ++kt) acc = MFMA(ldA(xs, mt, kt, l), fq[kt], acc);
      #pragma unroll
      for (int r = 0; r < 4; ++r)
        qs[(mt * 16 + g * 4 + r) * 72 + chq] = f2bf(acc[r]);
    }

    // ---- GEMM2: v_init = x * Wvi^T -> vis (bf16) ----
    #pragma unroll
    for (int nt = 0; nt < 2; ++nt) {
      short8 fi[4];
      #pragma unroll
      for (int kt = 0; kt < 4; ++kt) fi[kt] = wip[(nt * 64 + chq) * 16 + kt * 4 + g];
      const float bl = nt ? bil1 : bil0;
      #pragma unroll
      for (int mt = 0; mt < 4; ++mt) {
        f32x4 acc = {bl, bl, bl, bl};
        #pragma unroll
        for (int kt = 0; kt < 4; ++kt) acc = MFMA(ldA(xs, mt, kt, l), fi[kt], acc);
        #pragma unroll
        for (int rp = 0; rp < 2; ++rp) {
          const int px = mt * 16 + g * 4 + rp * 2;
          *(unsigned*)((char*)vis + (nt * 64 + chq) * 132 + px * 2) =
              pack_bf16(acc[rp * 2], acc[rp * 2 + 1]);
        }
      }
    }
    __syncthreads();   // all waves done with x-frag reads; qs/vis ready

    // ---- scores: partial q.k over this wave's 16 q-channels ----
    float qf[16];
    {
      const uint4* qp = (const uint4*)((const char*)qs + px_t * 144 + w * 32);
      uint4 u0 = qp[0], u1 = qp[1];
      unsigned uu[8] = {u0.x, u0.y, u0.z, u0.w, u1.x, u1.y, u1.z, u1.w};
      #pragma unroll
      for (int i = 0; i < 8; ++i) {
        qf[2 * i]     = __builtin_bit_cast(float, uu[i] << 16);
        qf[2 * i + 1] = __builtin_bit_cast(float, uu[i] & 0xffff0000u);
      }
    }
    const float* kb = kbuf + (size_t)b * kImgC * 64;
    #pragma unroll
    for (int j = 0; j < 9; ++j) {
      const int yy = y2 + j / 3 - 1, xx = x2 + j % 3 - 1;
      float s = 0.f;   // zero-padded tap => score exactly 0 (unfold semantics)
      if (yy >= 0 && yy < 128 && xx >= 0 && xx < 256) {
        const float4* kp = (const float4*)(kb + ((size_t)yy * 256 + xx) * 64 + w * 16);
        float4 k0 = kp[0], k1 = kp[1], k2 = kp[2], k3 = kp[3];
        s = qf[0]*k0.x + qf[1]*k0.y + qf[2]*k0.z + qf[3]*k0.w
          + qf[4]*k1.x + qf[5]*k1.y + qf[6]*k1.z + qf[7]*k1.w
          + qf[8]*k2.x + qf[9]*k2.y + qf[10]*k2.z + qf[11]*k2.w
          + qf[12]*k3.x + qf[13]*k3.y + qf[14]*k3.z + qf[15]*k3.w;
      }
      part[j * 256 + w * 64 + px_t] = s;
    }
    __syncthreads();

    // ---- softmax over 9 taps ----
    float a[9]; float mx = -1e30f;
    #pragma unroll
    for (int j = 0; j < 9; ++j) {
      float s = part[j * 256 + px_t] + part[j * 256 + 64 + px_t]
              + part[j * 256 + 128 + px_t] + part[j * 256 + 192 + px_t];
      a[j] = s; mx = fmaxf(mx, s);
    }
    float den = 0.f;
    #pragma unroll
    for (int j = 0; j < 9; ++j) { a[j] = __expf(a[j] - mx); den += a[j]; }
    const float inv = 1.f / den;

    // ---- t = v_init + sum_j a_j * v_win ----
    float tt[32];
    #pragma unroll
    for (int i = 0; i < 16; ++i) {
      tt[i]      = bf_up(vis[(w * 16 + i) * 66 + px_t]);
      tt[16 + i] = bf_up(vis[(64 + w * 16 + i) * 66 + px_t]);
    }
    const float* vb = vbuf + (size_t)b * kImgC * 128;
    #pragma unroll
    for (int j = 0; j < 9; ++j) {
      const int yy = y2 + j / 3 - 1, xx = x2 + j % 3 - 1;
      if (yy >= 0 && yy < 128 && xx >= 0 && xx < 256) {
        const float aj = a[j] * inv;
        const float* vrow = vb + ((size_t)yy * 256 + xx) * 128;
        const float4* vp = (const float4*)(vrow + w * 16);
        const float4* vq = (const float4*)(vrow + 64 + w * 16);
        float4 v0 = vp[0], v1 = vp[1], v2 = vp[2], v3 = vp[3];
        float4 u0 = vq[0], u1 = vq[1], u2 = vq[2], u3 = vq[3];
        tt[0]+=aj*v0.x; tt[1]+=aj*v0.y; tt[2]+=aj*v0.z; tt[3]+=aj*v0.w;
        tt[4]+=aj*v1.x; tt[5]+=aj*v1.y; tt[6]+=aj*v1.z; tt[7]+=aj*v1.w;
        tt[8]+=aj*v2.x; tt[9]+=aj*v2.y; tt[10]+=aj*v2.z; tt[11]+=aj*v2.w;
        tt[12]+=aj*v3.x; tt[13]+=aj*v3.y; tt[14]+=aj*v3.z; tt[15]+=aj*v3.w;
        tt[16]+=aj*u0.x; tt[17]+=aj*u0.y; tt[18]+=aj*u0.z; tt[19]+=aj*u0.w;
        tt[20]+=aj*u1.x; tt[21]+=aj*u1.y; tt[22]+=aj*u1.z; tt[23]+=aj*u1.w;
        tt[24]+=aj*u2.x; tt[25]+=aj*u2.y; tt[26]+=aj*u2.z; tt[27]+=aj*u2.w;
        tt[28]+=aj*u3.x; tt[29]+=aj*u3.y; tt[30]+=aj*u3.z; tt[31]+=aj*u3.w;
      }
    }
    // write t into xs as swizzled bf16 A-tile (jj-rotation -> spread banks)
    #pragma unroll
    for (int hh = 0; hh < 2; ++hh) {
      #pragma unroll
      for (int jj = 0; jj < 8; ++jj) {
        const int jp = (jj + (px_t >> 3)) & 7;
        const int ch = hh * 64 + w * 16 + 2 * jp;
        const int chunk = (ch >> 3) ^ (px_t & 7);
        *(unsigned*)(xs + px_t * 256 + chunk * 16 + (ch & 7) * 2) =
            pack_bf16(tt[hh * 16 + 2 * jp], tt[hh * 16 + 2 * jp + 1]);
      }
    }
    __syncthreads();

    // ---- GEMM3: out = t * Wout^T ----
    #pragma unroll
    for (int nt = 0; nt < 2; ++nt) {
      short8 fo[4];
      #pragma unroll
      for (int kt = 0; kt < 4; ++kt) fo[kt] = wop[(nt * 64 + chq) * 16 + kt * 4 + g];
      const float bl = nt ? bol1 : bol0;
      #pragma unroll
      for (int mt = 0; mt < 4; ++mt) {
        f32x4 acc = {bl, bl, bl, bl};
        #pragma unroll
        for (int kt = 0; kt < 4; ++kt) acc = MFMA(ldA(xs, mt, kt, l), fo[kt], acc);
        *(float4*)(out + fbase + (size_t)(nt * 64 + chq) * kImgF
                   + (size_t)y * 512 + x0 + mt * 16 + g * 4) =
            make_float4(acc[0], acc[1], acc[2], acc[3]);
      }
    }
  }
}

// ---------- launch ----------
extern "C" void kernel_launch(void* const* d_in, const int* in_sizes, int n_in,
                              void* d_out, int out_size, void* d_ws, size_t ws_size,
                              hipStream_t stream) {
  const float* h_prev = (const float*)d_in[0];
  const float* h_init = (const float*)d_in[1];
  const float* Wq   = (const float*)d_in[2];
  const float* bq   = (const float*)d_in[3];
  const float* Wk   = (const float*)d_in[4];
  const float* bk   = (const float*)d_in[5];
  const float* Wvp  = (const float*)d_in[6];
  const float* bvp  = (const float*)d_in[7];
  const float* Wvi  = (const float*)d_in[8];
  const float* bvi  = (const float*)d_in[9];
  const float* Wout = (const float*)d_in[10];
  const float* bout = (const float*)d_in[11];
  float* out = (float*)d_out;

  char* ws = (char*)d_ws;
  unsigned short* wbuf = (unsigned short*)ws;                  // 65536 shorts = 131072 B
  float* kbuf = (float*)(ws + 131072);                         // 65536*64 f32 = 16 MB
  float* vbuf = (float*)(ws + 131072 + (size_t)65536 * 64 * 4); // 65536*128 f32 = 32 MB

  cast_w<<<256, THREADS, 0, stream>>>(Wq, Wk, Wvp, Wvi, Wout, wbuf);
  coarse_kv<<<1024, THREADS, 0, stream>>>(h_prev, wbuf, bk, bvp, kbuf, vbuf);
  fine_fused<<<2048, THREADS, 0, stream>>>(h_init, wbuf, bq, bvi, bout,
                                           kbuf, vbuf, out);
}